// Round 1
// baseline (494.363 us; speedup 1.0000x reference)
//
#include <hip/hip_runtime.h>
#include <cstdint>
#include <cstddef>

// ---------------- types / helpers ----------------
typedef __attribute__((ext_vector_type(4))) float f32x4;
typedef __attribute__((ext_vector_type(8))) unsigned short u16x8;
typedef __attribute__((ext_vector_type(4))) unsigned short u16x4;
typedef __bf16 bf16x8 __attribute__((ext_vector_type(8)));

__device__ __forceinline__ unsigned short f2bf(float f) {
  unsigned u = __builtin_bit_cast(unsigned, f);
  u += 0x7FFF + ((u >> 16) & 1);            // round-to-nearest-even
  return (unsigned short)(u >> 16);
}

__device__ __forceinline__ void mfma16x16x32(f32x4& acc, u16x8 a, u16x8 b) {
  acc = __builtin_amdgcn_mfma_f32_16x16x32_bf16(
      __builtin_bit_cast(bf16x8, a), __builtin_bit_cast(bf16x8, b), acc, 0, 0, 0);
}

typedef __attribute__((address_space(1))) const unsigned int as1_u32;
typedef __attribute__((address_space(3))) unsigned int as3_u32;
__device__ __forceinline__ void load_lds16(const void* g, void* l) {
  __builtin_amdgcn_global_load_lds((as1_u32*)g, (as3_u32*)l, 16, 0, 0);
}

// ---------------- kernel 1: rope table ----------------
// tab[t][f] = (cos(t*invfreq(f)), sin(t*invfreq(f))), t<2048, f<64
__global__ void k_sincos(float2* __restrict__ tab) {
  int i = blockIdx.x * blockDim.x + threadIdx.x;
  if (i >= 2048 * 64) return;
  int t = i >> 6, f = i & 63;
  // invfreq = 10000^(-f/64) = exp(-f * ln(10000)/64)
  float inv = expf(-(float)f * 0.14391156831212787f);
  float ang = (float)t * inv;
  tab[i] = make_float2(cosf(ang), sinf(ang));
}

// ---------------- kernel 2: f32 -> bf16 convert ----------------
__global__ void k_cvt(const float* __restrict__ src, unsigned short* __restrict__ dst, int n4) {
  int stride = gridDim.x * blockDim.x;
  const float4* s = (const float4*)src;
  for (int i = blockIdx.x * blockDim.x + threadIdx.x; i < n4; i += stride) {
    float4 v = s[i];
    u16x4 o = { f2bf(v.x), f2bf(v.y), f2bf(v.z), f2bf(v.w) };
    *(u16x4*)(dst + (size_t)i * 4) = o;
  }
}

// ---------------- kernel 3: bf16 GEMM, C[M][N] = A[M][K] * Bt[N][K]^T ----------------
// 128x128 tile, BK=32, 4 waves (2x2), 16x16x32 MFMA, global_load_lds staging.
__global__ __launch_bounds__(256) void k_gemm_bt(
    const unsigned short* __restrict__ A, const unsigned short* __restrict__ Bt,
    float* __restrict__ C, int M, int N, int K) {
  __shared__ unsigned short lA[128 * 32];
  __shared__ unsigned short lB[128 * 32];
  const int tid = threadIdx.x;
  const int w = tid >> 6, lane = tid & 63;
  const int wm = w >> 1, wn = w & 1;
  const int m0 = blockIdx.y * 128, n0 = blockIdx.x * 128;
  const int lr = lane & 15, lg = lane >> 4;

  f32x4 acc[4][4];
#pragma unroll
  for (int i = 0; i < 4; i++)
#pragma unroll
    for (int j = 0; j < 4; j++) acc[i][j] = (f32x4){0.f, 0.f, 0.f, 0.f};

  // staging: wave w stages rows [w*32, w*32+32) of both tiles; one
  // global_load_lds(16B) moves 1KB = 16 rows (32 cols * 2B) per wave.
  const int srow = w * 32 + (lane >> 2);
  const int scol = (lane & 3) * 8;
  const unsigned short* gA = A + (size_t)(m0 + srow) * K + scol;
  const unsigned short* gB = Bt + (size_t)(n0 + srow) * K + scol;

  for (int kt = 0; kt < K; kt += 32) {
#pragma unroll
    for (int c = 0; c < 2; c++) {
      load_lds16(gA + (size_t)c * 16 * K + kt, &lA[(w * 32 + c * 16) * 32]);
      load_lds16(gB + (size_t)c * 16 * K + kt, &lB[(w * 32 + c * 16) * 32]);
    }
    __syncthreads();   // drains vmcnt before LDS reads
    u16x8 af[4], bf[4];
#pragma unroll
    for (int i = 0; i < 4; i++) af[i] = *(const u16x8*)&lA[(wm * 64 + i * 16 + lr) * 32 + lg * 8];
#pragma unroll
    for (int j = 0; j < 4; j++) bf[j] = *(const u16x8*)&lB[(wn * 64 + j * 16 + lr) * 32 + lg * 8];
#pragma unroll
    for (int i = 0; i < 4; i++)
#pragma unroll
      for (int j = 0; j < 4; j++) mfma16x16x32(acc[i][j], af[i], bf[j]);
    __syncthreads();   // protect LDS from next stage
  }
  // C/D layout: col = lane&15, row = (lane>>4)*4 + reg   [m89/m91 verified]
#pragma unroll
  for (int i = 0; i < 4; i++)
#pragma unroll
    for (int j = 0; j < 4; j++)
#pragma unroll
      for (int r = 0; r < 4; r++) {
        int row = m0 + wm * 64 + i * 16 + lg * 4 + r;
        int col = n0 + wn * 64 + j * 16 + lr;
        C[(size_t)row * N + col] = acc[i][j][r];
      }
}

// ---------------- kernel 4: build K side of new_past + RoPE'd K cache ----------------
// past layout (1,2,4,1024,128); qkv fp32 [1024][5120] (q|k|v); outk [4][2048][128]
__global__ void k_build_k(const float* __restrict__ past, const float* __restrict__ qkv,
                          float* __restrict__ outk, unsigned short* __restrict__ kr,
                          const float2* __restrict__ tab) {
  int idx = blockIdx.x * blockDim.x + threadIdx.x;
  if (idx >= 4 * 2048 * 64) return;
  int d0 = idx & 63;
  int t = (idx >> 6) & 2047;
  int h = idx >> 17;
  float v1, v2;
  if (t < 1024) {
    const float* p = past + ((size_t)h * 1024 + t) * 128;
    v1 = p[d0]; v2 = p[d0 + 64];
  } else {
    const float* p = qkv + (size_t)(t - 1024) * 5120 + 4096 + h * 128;
    v1 = p[d0]; v2 = p[d0 + 64];
  }
  float* o = outk + ((size_t)h * 2048 + t) * 128;
  o[d0] = v1; o[d0 + 64] = v2;                       // new_past stores PRE-RoPE k
  float2 cs = tab[t * 64 + d0];                      // reference RoPEs past keys too
  unsigned short* ko = kr + ((size_t)h * 2048 + t) * 128;
  ko[d0]      = f2bf(v1 * cs.x - v2 * cs.y);
  ko[d0 + 64] = f2bf(v2 * cs.x + v1 * cs.y);
}

// ---------------- kernel 5: build V side of new_past + transposed V cache ----------------
// vt [4][128][2048] so PV B-fragments are contiguous along keys
__global__ void k_build_v(const float* __restrict__ past, const float* __restrict__ qkv,
                          float* __restrict__ outv, unsigned short* __restrict__ vt) {
  int idx = blockIdx.x * blockDim.x + threadIdx.x;
  if (idx >= 4 * 2048 * 128) return;
  int d = idx & 127;
  int t = (idx >> 7) & 2047;
  int h = idx >> 18;
  float val = (t < 1024) ? past[4 * 1024 * 128 + ((size_t)h * 1024 + t) * 128 + d]
                         : qkv[(size_t)(t - 1024) * 5120 + 4608 + h * 128 + d];
  outv[((size_t)h * 2048 + t) * 128 + d] = val;
  vt[((size_t)h * 128 + d) * 2048 + t] = f2bf(val);
}

// ---------------- kernel 6: RoPE q -> bf16 [32][1024][128] ----------------
__global__ void k_rope_q(const float* __restrict__ qkv, unsigned short* __restrict__ qr,
                         const float2* __restrict__ tab) {
  int idx = blockIdx.x * blockDim.x + threadIdx.x;
  if (idx >= 32 * 1024 * 64) return;
  int d0 = idx & 63;
  int q = (idx >> 6) & 1023;
  int h = idx >> 16;
  const float* p = qkv + (size_t)q * 5120 + h * 128;
  float v1 = p[d0], v2 = p[d0 + 64];
  float2 cs = tab[(1024 + q) * 64 + d0];
  unsigned short* o = qr + ((size_t)h * 1024 + q) * 128;
  o[d0]      = f2bf(v1 * cs.x - v2 * cs.y);
  o[d0 + 64] = f2bf(v2 * cs.x + v1 * cs.y);
}

// ---------------- kernel 7: flash attention ----------------
// 1 wave / block, 16 q-rows of one head; KV tiles of 32; online softmax.
// grid = 32 heads * 64 qtiles.
__global__ __launch_bounds__(64) void k_attn(
    const unsigned short* __restrict__ qr,  // [32][1024][128]
    const unsigned short* __restrict__ kr,  // [4][2048][128] (RoPE'd)
    const unsigned short* __restrict__ vt,  // [4][128][2048]
    unsigned short* __restrict__ ctxb) {    // [1024][4096] bf16
  __shared__ unsigned short plds[16 * 40];  // P tile 16x32, pad to 40 (80B rows)
  const int bid = blockIdx.x;
  const int h = bid >> 6;
  const int qt = bid & 63;
  const int q0 = qt * 16;
  const int kvh = h >> 3;                   // N_REP = 8
  const int l = threadIdx.x;
  const int lr = l & 15, lg = l >> 4;

  u16x8 qf[4];
  {
    const unsigned short* qb = qr + ((size_t)(h * 1024 + q0 + lr)) * 128 + lg * 8;
#pragma unroll
    for (int ks = 0; ks < 4; ks++) qf[ks] = *(const u16x8*)(qb + ks * 32);
  }
  f32x4 acc[8];
#pragma unroll
  for (int i = 0; i < 8; i++) acc[i] = (f32x4){0.f, 0.f, 0.f, 0.f};
  float m_r[4] = {-1e30f, -1e30f, -1e30f, -1e30f};
  float l_r[4] = {0.f, 0.f, 0.f, 0.f};

  const int limit_base = 1024 + q0;
  const int ntiles = (1024 + q0 + 15) / 32 + 1;
  const float scale = 0.08838834764831845f;  // 1/sqrt(128)
  const unsigned short* kh = kr + (size_t)kvh * 2048 * 128;
  const unsigned short* vh = vt + (size_t)kvh * 128 * 2048;

  for (int t = 0; t < ntiles; t++) {
    const int kb = t * 32;
    // QK^T: S[16q][32k] as two 16x16 D tiles
    f32x4 s[2];
#pragma unroll
    for (int sub = 0; sub < 2; sub++) {
      f32x4 a = (f32x4){0.f, 0.f, 0.f, 0.f};
      const unsigned short* kp = kh + (size_t)(kb + sub * 16 + lr) * 128 + lg * 8;
#pragma unroll
      for (int ks = 0; ks < 4; ks++) {
        u16x8 kf = *(const u16x8*)(kp + ks * 32);
        mfma16x16x32(a, qf[ks], kf);
      }
      s[sub] = a;
    }
    // online softmax; lane's D entries: rows lg*4+rr, key col kb(+16)+lr
    const int key0 = kb + lr, key1 = kb + 16 + lr;
    float corr[4];
#pragma unroll
    for (int rr = 0; rr < 4; rr++) {
      const int limit = limit_base + lg * 4 + rr;
      float a0 = (key0 <= limit) ? s[0][rr] * scale : -1e30f;
      float a1 = (key1 <= limit) ? s[1][rr] * scale : -1e30f;
      float tmax = fmaxf(a0, a1);
#pragma unroll
      for (int off = 1; off < 16; off <<= 1) tmax = fmaxf(tmax, __shfl_xor(tmax, off));
      float mnew = fmaxf(m_r[rr], tmax);
      float c = __expf(m_r[rr] - mnew);
      float p0 = __expf(a0 - mnew);
      float p1 = __expf(a1 - mnew);
      float ps = p0 + p1;
#pragma unroll
      for (int off = 1; off < 16; off <<= 1) ps += __shfl_xor(ps, off);
      l_r[rr] = l_r[rr] * c + ps;
      m_r[rr] = mnew;
      corr[rr] = c;
      plds[(lg * 4 + rr) * 40 + lr] = f2bf(p0);
      plds[(lg * 4 + rr) * 40 + 16 + lr] = f2bf(p1);
    }
#pragma unroll
    for (int nt = 0; nt < 8; nt++)
#pragma unroll
      for (int rr = 0; rr < 4; rr++) acc[nt][rr] *= corr[rr];
    __syncthreads();  // P tile visible (transpose via LDS)
    u16x8 pf = *(const u16x8*)&plds[lr * 40 + lg * 8];
#pragma unroll
    for (int nt = 0; nt < 8; nt++) {
      const unsigned short* vp = vh + (size_t)(nt * 16 + lr) * 2048 + kb + lg * 8;
      u16x8 vf = *(const u16x8*)vp;
      mfma16x16x32(acc[nt], pf, vf);
    }
    __syncthreads();  // protect plds before next tile's writes
  }
  // epilogue: ctx[q][h*128+d] bf16
#pragma unroll
  for (int rr = 0; rr < 4; rr++) {
    float inv = 1.0f / l_r[rr];
    int row = q0 + lg * 4 + rr;
#pragma unroll
    for (int nt = 0; nt < 8; nt++)
      ctxb[(size_t)row * 4096 + h * 128 + nt * 16 + lr] = f2bf(acc[nt][rr] * inv);
  }
}

// ---------------- launch ----------------
extern "C" void kernel_launch(void* const* d_in, const int* in_sizes, int n_in,
                              void* d_out, int out_size, void* d_ws, size_t ws_size,
                              hipStream_t stream) {
  (void)in_sizes; (void)n_in; (void)out_size; (void)ws_size;
  const float* hs   = (const float*)d_in[0];
  const float* past = (const float*)d_in[1];
  // d_in[2] attention_mask: pure causal, synthesized analytically
  const float* Wq = (const float*)d_in[3];
  const float* Wk = (const float*)d_in[4];
  const float* Wv = (const float*)d_in[5];
  const float* Wo = (const float*)d_in[6];

  float* out_attn = (float*)d_out;                 // [1024][4096]
  float* out_pk = out_attn + 4194304;              // [4][2048][128]
  float* out_pv = out_pk + 1048576;                // [4][2048][128]

  char* ws = (char*)d_ws;
  unsigned short* hs_bf   = (unsigned short*)(ws);                // 8 MB
  unsigned short* wqkv_bf = (unsigned short*)(ws + 8388608);      // 40 MB [5120][4096]
  unsigned short* wo_bf   = (unsigned short*)(ws + 50331648);     // 32 MB [4096][4096]
  float*          qkv     = (float*)(ws + 83886080);              // 20 MB [1024][5120]
  unsigned short* qr      = (unsigned short*)(ws + 104857600);    // 8 MB  [32][1024][128]
  unsigned short* kr      = (unsigned short*)(ws + 113246208);    // 2 MB  [4][2048][128]
  unsigned short* vt      = (unsigned short*)(ws + 115343360);    // 2 MB  [4][128][2048]
  unsigned short* ctxb    = (unsigned short*)(ws + 117440512);    // 8 MB  [1024][4096]
  float2*         tab     = (float2*)(ws + 125829120);            // 1 MB  [2048][64]

  k_sincos<<<512, 256, 0, stream>>>(tab);
  k_cvt<<<2048, 256, 0, stream>>>(hs, hs_bf, 4194304 / 4);
  k_cvt<<<2048, 256, 0, stream>>>(Wq, wqkv_bf, 16777216 / 4);
  k_cvt<<<2048, 256, 0, stream>>>(Wk, wqkv_bf + 16777216, 2097152 / 4);
  k_cvt<<<2048, 256, 0, stream>>>(Wv, wqkv_bf + 18874368, 2097152 / 4);
  k_cvt<<<2048, 256, 0, stream>>>(Wo, wo_bf, 16777216 / 4);

  dim3 g1(5120 / 128, 1024 / 128);
  k_gemm_bt<<<g1, 256, 0, stream>>>(hs_bf, wqkv_bf, qkv, 1024, 5120, 4096);

  k_build_k<<<2048, 256, 0, stream>>>(past, qkv, out_pk, kr, tab);
  k_build_v<<<4096, 256, 0, stream>>>(past, qkv, out_pv, vt);
  k_rope_q<<<8192, 256, 0, stream>>>(qkv, qr, tab);

  k_attn<<<32 * 64, 64, 0, stream>>>(qr, kr, vt, ctxb);

  dim3 g2(4096 / 128, 1024 / 128);
  k_gemm_bt<<<g2, 256, 0, stream>>>(ctxb, wo_bf, out_attn, 1024, 4096, 4096);
}